// Round 1
// baseline (388.858 us; speedup 1.0000x reference)
//
#include <hip/hip_runtime.h>
#include <hip/hip_bf16.h>

// Problem constants (from reference): B=1, T=2048, H=16, D=64, G=16, HKV=1,
// BS=64, S=16, NB=32. K/V are effectively [T][D] contiguous since HKV=1.
#define T_    2048
#define H_    16
#define D_    64
#define S_    16
#define BS_   64
#define SCALE 0.125f                  // 1/sqrt(64)
#define L2E   1.4426950408889634f     // log2(e)
#define TPAD  65                      // +1 pad: 64-lane row/col access <=2-way bank alias

__global__ __launch_bounds__(256) void nsa_fwd(
    const float* __restrict__ Q, const float* __restrict__ K,
    const float* __restrict__ V, const int* __restrict__ BI,
    float* __restrict__ Out)
{
    __shared__ float qs[H_ * D_];       // 4 KB: Q rows for all 16 heads of this token
    __shared__ float ks[BS_ * TPAD];    // 16.25 KB padded K tile
    __shared__ float vs[BS_ * TPAD];    // 16.25 KB padded V tile
    __shared__ float ps[H_ * BS_];      // 4 KB: softmax P transpose buffer (wave-private rows)
    __shared__ int   bidx[S_];

    const int t    = blockIdx.x;
    const int tid  = threadIdx.x;
    const int lane = tid & 63;
    const int wv   = tid >> 6;      // wave 0..3
    const int h0   = wv * 4;        // this wave owns heads h0..h0+3

    // Stage Q (1024 floats = 256 float4, one per thread) + block indices
    {
        const float4* q4 = (const float4*)(Q + (size_t)t * (H_ * D_));
        ((float4*)qs)[tid] = q4[tid];
    }
    if (tid < S_) bidx[tid] = BI[t * S_ + tid];
    __syncthreads();

    float m[4], l[4], o[4];
#pragma unroll
    for (int i = 0; i < 4; ++i) { m[i] = -1e30f; l[i] = 0.0f; o[i] = 0.0f; }

    for (int s = 0; s < S_; ++s) {
        const int blk = bidx[s];
        // ---- stage K/V block (each 64x64 f32, contiguous 16 KB in global) ----
        const float4* kg = (const float4*)(K + (size_t)blk * (BS_ * D_));
        const float4* vg = (const float4*)(V + (size_t)blk * (BS_ * D_));
#pragma unroll
        for (int u = 0; u < 4; ++u) {
            const int f = tid + u * 256;          // float4 index 0..1023
            const int r = f >> 4;                 // key row 0..63
            const int c = (f & 15) << 2;          // float col 0..60
            const float4 kq = kg[f];
            const float4 vq = vg[f];
            float* kd = &ks[r * TPAD + c];
            kd[0] = kq.x; kd[1] = kq.y; kd[2] = kq.z; kd[3] = kq.w;
            float* vd = &vs[r * TPAD + c];
            vd[0] = vq.x; vd[1] = vq.y; vd[2] = vq.z; vd[3] = vq.w;
        }
        __syncthreads();

        // ---- QK^T: lane = key j, 4 heads per wave ----
        float acc[4] = {0.f, 0.f, 0.f, 0.f};
        const float* krow = &ks[lane * TPAD];
#pragma unroll
        for (int d4 = 0; d4 < 16; ++d4) {
            const float k0 = krow[d4 * 4 + 0];
            const float k1 = krow[d4 * 4 + 1];
            const float k2 = krow[d4 * 4 + 2];
            const float k3 = krow[d4 * 4 + 3];
#pragma unroll
            for (int hh = 0; hh < 4; ++hh) {
                const float4 qv = ((const float4*)qs)[(h0 + hh) * 16 + d4]; // broadcast
                acc[hh] += qv.x * k0 + qv.y * k1 + qv.z * k2 + qv.w * k3;
            }
        }

        // ---- online softmax update (per head) ----
        const int  pos   = blk * BS_ + lane;
        const bool valid = (pos <= t);
        float alpha[4];
#pragma unroll
        for (int hh = 0; hh < 4; ++hh) {
            float sc = valid ? acc[hh] * SCALE : -1e30f;
            float bm = sc;
#pragma unroll
            for (int off = 32; off > 0; off >>= 1)
                bm = fmaxf(bm, __shfl_xor(bm, off));
            const float mn = fmaxf(m[hh], bm);
            alpha[hh] = exp2f((m[hh] - mn) * L2E);
            const float p = exp2f((sc - mn) * L2E);
            float psum = p;
#pragma unroll
            for (int off = 32; off > 0; off >>= 1)
                psum += __shfl_xor(psum, off);
            l[hh] = l[hh] * alpha[hh] + psum;
            m[hh] = mn;
            ps[(h0 + hh) * BS_ + lane] = p;   // wave-private row; same-wave RAW below
        }
#pragma unroll
        for (int hh = 0; hh < 4; ++hh) o[hh] *= alpha[hh];

        // ---- PV: lane = dim d ----
#pragma unroll 4
        for (int j4 = 0; j4 < 16; ++j4) {
            const float4 p0 = *(const float4*)&ps[(h0 + 0) * BS_ + j4 * 4];
            const float4 p1 = *(const float4*)&ps[(h0 + 1) * BS_ + j4 * 4];
            const float4 p2 = *(const float4*)&ps[(h0 + 2) * BS_ + j4 * 4];
            const float4 p3 = *(const float4*)&ps[(h0 + 3) * BS_ + j4 * 4];
            const float v0 = vs[(j4 * 4 + 0) * TPAD + lane];
            const float v1 = vs[(j4 * 4 + 1) * TPAD + lane];
            const float v2 = vs[(j4 * 4 + 2) * TPAD + lane];
            const float v3 = vs[(j4 * 4 + 3) * TPAD + lane];
            o[0] += p0.x * v0 + p0.y * v1 + p0.z * v2 + p0.w * v3;
            o[1] += p1.x * v0 + p1.y * v1 + p1.z * v2 + p1.w * v3;
            o[2] += p2.x * v0 + p2.y * v1 + p2.z * v2 + p2.w * v3;
            o[3] += p3.x * v0 + p3.y * v1 + p3.z * v2 + p3.w * v3;
        }
        __syncthreads();   // protect ks/vs before next iteration's staging
    }

    // ---- epilogue: Out[t][h][d] = o/l, lane = d ----
    float* outp = Out + (size_t)t * (H_ * D_);
#pragma unroll
    for (int hh = 0; hh < 4; ++hh) {
        outp[(h0 + hh) * D_ + lane] = o[hh] / l[hh];
    }
}

extern "C" void kernel_launch(void* const* d_in, const int* in_sizes, int n_in,
                              void* d_out, int out_size, void* d_ws, size_t ws_size,
                              hipStream_t stream) {
    const float* Q  = (const float*)d_in[0];
    const float* K  = (const float*)d_in[1];
    const float* V  = (const float*)d_in[2];
    const int*   BI = (const int*)d_in[3];
    float*       Out = (float*)d_out;
    nsa_fwd<<<dim3(T_), dim3(256), 0, stream>>>(Q, K, V, BI, Out);
}

// Round 2
// 125.480 us; speedup vs baseline: 3.0990x; 3.0990x over previous
//
#include <hip/hip_runtime.h>
#include <hip/hip_bf16.h>

// B=1, T=2048, H=16, D=64, G=16, HKV=1, BS=64, S=16, NB=32.
// Strategy: one wave per token. All 16 heads = M dim of mfma_f32_16x16x32_f16.
// Per selected block: QK via 8 MFMAs (4 n-tiles x 2 k-steps), online softmax in
// C-layout registers (16-lane shfl reductions), P transposed C->A layout through
// a per-wave 16x72-f16 LDS buffer, PV via 8 MFMAs, l via ones-column MFMA.
// K and V^T are pre-converted to f16 in d_ws by a prepass kernel; B-fragments
// load DIRECTLY from global (L1/L2 resident) -- no K/V LDS staging, no barriers.
#define T_    2048
#define H_    16
#define D_    64
#define S_    16
#define BS_   64
#define CEXP  0.1803368801111204f   // SCALE * log2(e) = 0.125 * 1.442695

typedef _Float16 f16x8 __attribute__((ext_vector_type(8)));
typedef float    f32x4 __attribute__((ext_vector_type(4)));

#define MFMA16(a, b, c) __builtin_amdgcn_mfma_f32_16x16x32_f16((a), (b), (c), 0, 0, 0)

// ---- prepass: K -> f16 [key][64]; V -> f16 transposed [dim][2048] ----
__global__ __launch_bounds__(256) void nsa_prep(
    const float* __restrict__ K, const float* __restrict__ V,
    _Float16* __restrict__ Kf, _Float16* __restrict__ Vt)
{
    const int i = blockIdx.x * 256 + threadIdx.x;   // 0 .. 131071
    Kf[i] = (_Float16)K[i];
    const int d = i >> 11;        // dim   0..63
    const int t = i & 2047;       // token 0..2047
    Vt[i] = (_Float16)V[t * D_ + d];
}

__global__ __launch_bounds__(256) void nsa_mfma(
    const float* __restrict__ Q, const int* __restrict__ BI,
    const _Float16* __restrict__ Kf, const _Float16* __restrict__ Vt,
    float* __restrict__ Out)
{
    __shared__ _Float16 P16[4][16 * 72];   // per-wave P transpose buffer (stride 72 f16 = 16B-aligned rows)

    const int tid  = threadIdx.x;
    const int wv   = tid >> 6;
    const int lane = tid & 63;
    const int t    = blockIdx.x * 4 + wv;
    const int g    = lane >> 4;    // quad 0..3
    const int c    = lane & 15;    // col / m-index

    // ---- Q A-fragments: A[m=c][k = ks*32 + g*8 + j], f32 -> f16 in regs ----
    f16x8 qa[2];
    {
        const float* qp = Q + ((size_t)t * H_ + c) * D_ + g * 8;
#pragma unroll
        for (int ks = 0; ks < 2; ++ks) {
            const float4 x = *(const float4*)(qp + ks * 32);
            const float4 y = *(const float4*)(qp + ks * 32 + 4);
            qa[ks] = (f16x8){(_Float16)x.x, (_Float16)x.y, (_Float16)x.z, (_Float16)x.w,
                             (_Float16)y.x, (_Float16)y.y, (_Float16)y.z, (_Float16)y.w};
        }
    }

    // ones-column B fragment for the l (row-sum) accumulator: B[k][0] = 1
    const _Float16 ov = (c == 0) ? (_Float16)1.0f : (_Float16)0.0f;
    const f16x8 lb = (f16x8){ov, ov, ov, ov, ov, ov, ov, ov};

    f32x4 o[4], lt;
#pragma unroll
    for (int nt = 0; nt < 4; ++nt) o[nt] = (f32x4){0.f, 0.f, 0.f, 0.f};
    lt = (f32x4){0.f, 0.f, 0.f, 0.f};
    float mrow[4] = {-1e30f, -1e30f, -1e30f, -1e30f};

    _Float16* pbuf = &P16[wv][0];

    for (int s = 0; s < S_; ++s) {
        const int blk = BI[t * S_ + s];

        // ---- B-fragments straight from global (f16, L1/L2-hit) ----
        // K: B[k=dim][n=key] = Kf[(blk*64 + nt*16 + c)*64 + ks*32 + g*8 .. +7]
        f16x8 kb[4][2], vb[4][2];
        {
            const _Float16* kp = Kf + ((blk * BS_ + c) * D_) + g * 8;
            const _Float16* vp = Vt + (size_t)c * T_ + blk * BS_ + g * 8;
#pragma unroll
            for (int nt = 0; nt < 4; ++nt) {
#pragma unroll
                for (int ks = 0; ks < 2; ++ks) {
                    kb[nt][ks] = *(const f16x8*)(kp + nt * 16 * D_ + ks * 32);
                    vb[nt][ks] = *(const f16x8*)(vp + (size_t)nt * 16 * T_ + ks * 32);
                }
            }
        }

        // ---- QK^T: scores S[head=4g+r][key = nt*16 + c] in C-layout ----
        f32x4 sc[4];
#pragma unroll
        for (int nt = 0; nt < 4; ++nt) {
            sc[nt] = MFMA16(qa[0], kb[nt][0], ((f32x4){0.f, 0.f, 0.f, 0.f}));
            sc[nt] = MFMA16(qa[1], kb[nt][1], sc[nt]);
        }

        // ---- causal mask validity (per n-tile; col = c, same for all rows) ----
        bool valid[4];
#pragma unroll
        for (int nt = 0; nt < 4; ++nt) valid[nt] = (blk * BS_ + nt * 16 + c) <= t;

        // ---- online softmax: row reductions across the 16 lanes of quad g ----
        float alpha[4];
#pragma unroll
        for (int r = 0; r < 4; ++r) {
            float mx = -1e30f;
#pragma unroll
            for (int nt = 0; nt < 4; ++nt) mx = fmaxf(mx, valid[nt] ? sc[nt][r] : -1e30f);
            mx = fmaxf(mx, __shfl_xor(mx, 1));
            mx = fmaxf(mx, __shfl_xor(mx, 2));
            mx = fmaxf(mx, __shfl_xor(mx, 4));
            mx = fmaxf(mx, __shfl_xor(mx, 8));
            const float mn = fmaxf(mrow[r], mx);
            alpha[r] = exp2f((mrow[r] - mn) * CEXP);
            mrow[r] = mn;
        }

        // ---- p = exp2((sc-m)*C), write f16 to LDS in [head][key] layout ----
#pragma unroll
        for (int nt = 0; nt < 4; ++nt) {
#pragma unroll
            for (int r = 0; r < 4; ++r) {
                const float p = valid[nt] ? exp2f((sc[nt][r] - mrow[r]) * CEXP) : 0.f;
                pbuf[(4 * g + r) * 72 + nt * 16 + c] = (_Float16)p;
            }
        }

        // ---- rescale running accumulators (per-row alpha) ----
#pragma unroll
        for (int nt = 0; nt < 4; ++nt) {
#pragma unroll
            for (int r = 0; r < 4; ++r) o[nt][r] *= alpha[r];
        }
#pragma unroll
        for (int r = 0; r < 4; ++r) lt[r] *= alpha[r];

        // ---- read P as A-fragments (same wave: compiler inserts lgkmcnt) ----
        f16x8 pa[2];
#pragma unroll
        for (int ks = 0; ks < 2; ++ks)
            pa[ks] = *(const f16x8*)(pbuf + c * 72 + ks * 32 + g * 8);

        // ---- PV (+ l via ones column) ----
#pragma unroll
        for (int nt = 0; nt < 4; ++nt) {
            o[nt] = MFMA16(pa[0], vb[nt][0], o[nt]);
            o[nt] = MFMA16(pa[1], vb[nt][1], o[nt]);
        }
        lt = MFMA16(pa[0], lb, lt);
        lt = MFMA16(pa[1], lb, lt);
    }

    // ---- epilogue: Out[t][head=4g+r][dim=nt*16+c] = o / l ----
    float* outp = Out + (size_t)t * (H_ * D_);
#pragma unroll
    for (int r = 0; r < 4; ++r) {
        const float lr  = __shfl(lt[r], lane & 48);   // lane (g,0) holds row sum
        const float inv = 1.0f / lr;
#pragma unroll
        for (int nt = 0; nt < 4; ++nt)
            outp[(4 * g + r) * D_ + nt * 16 + c] = o[nt][r] * inv;
    }
}

extern "C" void kernel_launch(void* const* d_in, const int* in_sizes, int n_in,
                              void* d_out, int out_size, void* d_ws, size_t ws_size,
                              hipStream_t stream) {
    const float* Q  = (const float*)d_in[0];
    const float* K  = (const float*)d_in[1];
    const float* V  = (const float*)d_in[2];
    const int*   BI = (const int*)d_in[3];
    float*       Out = (float*)d_out;

    _Float16* Kf = (_Float16*)d_ws;                 // 2048*64 f16 = 256 KB
    _Float16* Vt = Kf + (size_t)T_ * D_;            // 64*2048 f16 = 256 KB

    nsa_prep<<<dim3((T_ * D_) / 256), dim3(256), 0, stream>>>(K, V, Kf, Vt);
    nsa_mfma<<<dim3(T_ / 4), dim3(256), 0, stream>>>(Q, BI, Kf, Vt, Out);
}